// Round 10
// baseline (230.248 us; speedup 1.0000x reference)
//
#include <hip/hip_runtime.h>

#define N_NODES 50000
#define N_EDGES 800000
#define E_TOT   850000            // N_EDGES + N_NODES self loops
#define IN_CH   128
#define HID     64
#define HEADS   4
#define C1      256               // HEADS*HID
#define OUT_CH  64
#define NEG_SLOPE 0.2f
#define EPSV    1e-16f

typedef _Float16 half_t;
typedef _Float16 half2_t __attribute__((ext_vector_type(2)));
typedef _Float16 half8_t __attribute__((ext_vector_type(8)));
typedef float f32x4 __attribute__((ext_vector_type(4)));

__device__ __forceinline__ float lrelu(float v) {
    return (v > 0.f) ? v : NEG_SLOPE * v;
}

__device__ __forceinline__ void acc8(float (&a)[8], float w, float4 r) {
    half2_t p;
    p = __builtin_bit_cast(half2_t, r.x); a[0] = fmaf(w, (float)p[0], a[0]); a[1] = fmaf(w, (float)p[1], a[1]);
    p = __builtin_bit_cast(half2_t, r.y); a[2] = fmaf(w, (float)p[0], a[2]); a[3] = fmaf(w, (float)p[1], a[3]);
    p = __builtin_bit_cast(half2_t, r.z); a[4] = fmaf(w, (float)p[0], a[4]); a[5] = fmaf(w, (float)p[1], a[5]);
    p = __builtin_bit_cast(half2_t, r.w); a[6] = fmaf(w, (float)p[0], a[6]); a[7] = fmaf(w, (float)p[1], a[7]);
}

// ---------------- fused: weight prep (blocks [0,NPREP)) + edge count+rank (rest) ----------------
#define NPREP ((IN_CH * C1 + C1 * HID + 255) / 256)    // 192
#define NCNT  ((E_TOT + 255) / 256)                    // 3321
__global__ __launch_bounds__(256) void k_count_prep(
    const int* __restrict__ ei, int* __restrict__ deg, int* __restrict__ erank,
    const float* __restrict__ W1, const float* __restrict__ W2,
    half_t* __restrict__ W1T, half_t* __restrict__ W2T) {
    const int gb = blockIdx.x;
    const int tid = threadIdx.x;
    if (gb < NPREP) {
        int i = gb * 256 + tid;
        if (i < IN_CH * C1) {
            int c = i >> 7, k = i & 127;
            W1T[i] = (half_t)W1[k * C1 + c];
        }
        int j = i - IN_CH * C1;
        if (j >= 0 && j < C1 * HID) {
            int c = j >> 8, k = j & 255;
            W2T[j] = (half_t)W2[k * HID + c];
        }
    } else {
        int e = (gb - NPREP) * 256 + tid;
        if (e < E_TOT) {
            int d = (e < N_EDGES) ? ei[N_EDGES + e] : (e - N_EDGES);
            erank[e] = atomicAdd(&deg[d], 1);
        }
    }
}

#define SCAN_CH 1024
#define NB_SCAN ((N_NODES + SCAN_CH - 1) / SCAN_CH)   // 49

__global__ __launch_bounds__(256) void k_bsum(const int* __restrict__ deg,
                                              int* __restrict__ bsum) {
    const int b = blockIdx.x;
    const int tid = threadIdx.x;
    int sum = 0;
    for (int i = tid; i < SCAN_CH; i += 256) {
        int idx = b * SCAN_CH + i;
        sum += (idx < N_NODES) ? deg[idx] : 0;
    }
    #pragma unroll
    for (int d = 1; d < 64; d <<= 1) sum += __shfl_xor(sum, d, 64);
    __shared__ int ws[4];
    if ((tid & 63) == 0) ws[tid >> 6] = sum;
    __syncthreads();
    if (tid == 0) bsum[b] = ws[0] + ws[1] + ws[2] + ws[3];
}

// scan with fused block-offset prefix (reads bsum directly)
__global__ __launch_bounds__(1024) void k_scanf(const int* __restrict__ deg,
                                                const int* __restrict__ bsum,
                                                int* __restrict__ rowptr) {
    __shared__ int wsum[16];
    __shared__ int boff_s;
    const int b = blockIdx.x;
    const int tid = threadIdx.x;
    const int lane = tid & 63;
    const int wv = tid >> 6;                      // 16 waves
    if (wv == 0) {                                // block prefix from bsum[0..b)
        int v = (lane < b) ? bsum[lane] : 0;      // b <= 48 < 64
        #pragma unroll
        for (int d = 1; d < 64; d <<= 1) v += __shfl_xor(v, d, 64);
        if (lane == 0) boff_s = v;
    }
    if (b == 0 && tid == 0) rowptr[N_NODES] = E_TOT;
    const int i = b * SCAN_CH + tid;
    int v = (i < N_NODES) ? deg[i] : 0;
    int s = v;
    #pragma unroll
    for (int d = 1; d < 64; d <<= 1) {
        int t = __shfl_up(s, d, 64);
        if (lane >= d) s += t;
    }
    if (lane == 63) wsum[wv] = s;
    __syncthreads();
    if (wv == 0 && lane < 16) {
        int w = wsum[lane];
        #pragma unroll
        for (int d = 1; d < 16; d <<= 1) {
            int t = __shfl_up(w, d, 64);
            if (lane >= d) w += t;
        }
        wsum[lane] = w;
    }
    __syncthreads();
    int excl = boff_s + ((wv > 0) ? wsum[wv - 1] : 0) + (s - v);
    if (i < N_NODES) rowptr[i] = excl;
}

// ---------------- scatter: atomic-free (pos = rowptr[d] + precomputed rank) ----------------
__global__ void k_scatter(const int* __restrict__ ei, const int* __restrict__ erank,
                          const int* __restrict__ rowptr, int* __restrict__ csr_src) {
    int e = blockIdx.x * blockDim.x + threadIdx.x;
    if (e >= E_TOT) return;
    int s, d;
    if (e < N_EDGES) { s = ei[e]; d = ei[N_EDGES + e]; }
    else             { s = d = e - N_EDGES; }
    csr_src[rowptr[d] + erank[e]] = s;
}

// ---------------- GEMM1 (MFMA fp16): h1 = x @ W1, 32x256 tile, K=128; fused logit1 ----------------
#define XS1_LD 136
#define HS1_LD 264
__global__ __launch_bounds__(256) void k_gemm1(
    const float* __restrict__ x, const half_t* __restrict__ W1T,
    const float* __restrict__ a_s1, const float* __restrict__ a_d1,
    half_t* __restrict__ h1h, float* __restrict__ l1s, float* __restrict__ l1d) {
    __shared__ half_t xs[32 * XS1_LD];            // 8.7 KB
    __shared__ half_t hs[32 * HS1_LD];            // 16.9 KB
    const int base = blockIdx.x * 32;
    const int rows = min(32, N_NODES - base);
    const int tid = threadIdx.x;
    // stage x tile as fp16
    for (int idx = tid; idx < 32 * 16; idx += 256) {
        int row = idx >> 4, c8 = (idx & 15) * 8;
        half8_t hv = {0, 0, 0, 0, 0, 0, 0, 0};
        if (row < rows) {
            const float4 v0 = *(const float4*)(x + (size_t)(base + row) * IN_CH + c8);
            const float4 v1 = *(const float4*)(x + (size_t)(base + row) * IN_CH + c8 + 4);
            hv[0] = (half_t)v0.x; hv[1] = (half_t)v0.y; hv[2] = (half_t)v0.z; hv[3] = (half_t)v0.w;
            hv[4] = (half_t)v1.x; hv[5] = (half_t)v1.y; hv[6] = (half_t)v1.z; hv[7] = (half_t)v1.w;
        }
        *(half8_t*)(xs + row * XS1_LD + c8) = hv;
    }
    __syncthreads();
    const int lane = tid & 63;
    const int w = tid >> 6;
    const int cw = w * 64;                        // wave's 64-col slice
    const int lr = lane & 15;
    const int lg = lane >> 4;
    f32x4 acc[2][4];
    #pragma unroll
    for (int i = 0; i < 2; ++i)
        #pragma unroll
        for (int j = 0; j < 4; ++j)
            #pragma unroll
            for (int r = 0; r < 4; ++r) acc[i][j][r] = 0.f;

    #pragma unroll
    for (int kt = 0; kt < 4; ++kt) {
        const int k0 = kt * 32 + lg * 8;
        half8_t A0 = *(const half8_t*)(xs + lr * XS1_LD + k0);
        half8_t A1 = *(const half8_t*)(xs + (16 + lr) * XS1_LD + k0);
        #pragma unroll
        for (int ct = 0; ct < 4; ++ct) {
            half8_t B = *(const half8_t*)(W1T + (size_t)(cw + ct * 16 + lr) * IN_CH + k0);
            acc[0][ct] = __builtin_amdgcn_mfma_f32_16x16x32_f16(A0, B, acc[0][ct], 0, 0, 0);
            acc[1][ct] = __builtin_amdgcn_mfma_f32_16x16x32_f16(A1, B, acc[1][ct], 0, 0, 0);
        }
    }
    // C layout: col = lane&15, row = (lane>>4)*4 + r  -> LDS transpose, coalesced store
    #pragma unroll
    for (int rt = 0; rt < 2; ++rt)
        #pragma unroll
        for (int ct = 0; ct < 4; ++ct)
            #pragma unroll
            for (int r = 0; r < 4; ++r)
                hs[(rt * 16 + lg * 4 + r) * HS1_LD + cw + ct * 16 + lr] = (half_t)acc[rt][ct][r];
    __syncthreads();
    for (int idx = tid; idx < 32 * 32; idx += 256) {
        int row = idx >> 5, c8 = (idx & 31) * 8;
        if (row < rows)
            *(float4*)(h1h + (size_t)(base + row) * C1 + c8) = *(const float4*)(hs + row * HS1_LD + c8);
    }
    // fused logit1: wave w handles rows w*8..w*8+7; lane covers ch lane*4..+3
    {
        const int c4l = lane * 4;
        const float4 av = *(const float4*)(a_s1 + c4l);
        const float4 dv = *(const float4*)(a_d1 + c4l);
        #pragma unroll
        for (int i = 0; i < 8; ++i) {
            int row = w * 8 + i;
            if (row < rows) {
                float2 rr = *(const float2*)(hs + row * HS1_LD + c4l);
                half2_t ha = __builtin_bit_cast(half2_t, rr.x);
                half2_t hb = __builtin_bit_cast(half2_t, rr.y);
                float ps = (float)ha[0] * av.x + (float)ha[1] * av.y + (float)hb[0] * av.z + (float)hb[1] * av.w;
                float pd = (float)ha[0] * dv.x + (float)ha[1] * dv.y + (float)hb[0] * dv.z + (float)hb[1] * dv.w;
                #pragma unroll
                for (int d = 1; d < 16; d <<= 1) {
                    ps += __shfl_xor(ps, d, 64);
                    pd += __shfl_xor(pd, d, 64);
                }
                if ((lane & 15) == 0) {
                    int hh = lane >> 4;
                    l1s[(base + row) * HEADS + hh] = ps;
                    l1d[(base + row) * HEADS + hh] = pd;
                }
            }
        }
    }
}

// ---------------- agg1: half-wave per edge, 8 fp16 ch/lane, 8-deep unroll ----------------
__global__ __launch_bounds__(256) void k_agg1(
    const half_t* __restrict__ h1h, const float* __restrict__ l1s, const float* __restrict__ l1d,
    const int* __restrict__ rowptr, const int* __restrict__ csr_src,
    const float* __restrict__ b1, half_t* __restrict__ out1h) {
    const int tid = threadIdx.x;
    const int lane = tid & 63;
    const int wv = tid >> 6;
    const int n = blockIdx.x * 4 + wv;
    if (n >= N_NODES) return;                     // no syncthreads below
    const int beg = rowptr[n], end = rowptr[n + 1];
    const float4 ldv = *(const float4*)(l1d + (size_t)n * 4);
    const int half = lane >> 5;                   // edge stream 0/1
    const int l32 = lane & 31;
    const int c8 = l32 * 8;                       // this lane's 8 channels
    const int hh = l32 >> 3;                      // head of those channels
    const float ldh = (hh & 2) ? ((hh & 1) ? ldv.w : ldv.z) : ((hh & 1) ? ldv.y : ldv.x);
    const float* l1sh = l1s + hh;
    const float4* hrows = (const float4*)h1h;     // 32 float4 per row
    float a[8] = {0.f, 0.f, 0.f, 0.f, 0.f, 0.f, 0.f, 0.f};
    float dn = 0.f;
    int e = beg + half;
    // 8 edges in flight per half-wave (16 per wave)
    for (; e + 14 < end; e += 16) {
        int s0 = csr_src[e],      s1 = csr_src[e + 2],  s2 = csr_src[e + 4],  s3 = csr_src[e + 6];
        int s4 = csr_src[e + 8],  s5 = csr_src[e + 10], s6 = csr_src[e + 12], s7 = csr_src[e + 14];
        float4 r0 = hrows[s0 * 32 + l32];
        float4 r1 = hrows[s1 * 32 + l32];
        float4 r2 = hrows[s2 * 32 + l32];
        float4 r3 = hrows[s3 * 32 + l32];
        float4 r4 = hrows[s4 * 32 + l32];
        float4 r5 = hrows[s5 * 32 + l32];
        float4 r6 = hrows[s6 * 32 + l32];
        float4 r7 = hrows[s7 * 32 + l32];
        float g0 = l1sh[s0 * 4] + ldh;
        float g1 = l1sh[s1 * 4] + ldh;
        float g2 = l1sh[s2 * 4] + ldh;
        float g3 = l1sh[s3 * 4] + ldh;
        float g4 = l1sh[s4 * 4] + ldh;
        float g5 = l1sh[s5 * 4] + ldh;
        float g6 = l1sh[s6 * 4] + ldh;
        float g7 = l1sh[s7 * 4] + ldh;
        float w0 = __expf(lrelu(g0));
        float w1 = __expf(lrelu(g1));
        float w2 = __expf(lrelu(g2));
        float w3 = __expf(lrelu(g3));
        float w4 = __expf(lrelu(g4));
        float w5 = __expf(lrelu(g5));
        float w6 = __expf(lrelu(g6));
        float w7 = __expf(lrelu(g7));
        dn += ((w0 + w1) + (w2 + w3)) + ((w4 + w5) + (w6 + w7));
        acc8(a, w0, r0);
        acc8(a, w1, r1);
        acc8(a, w2, r2);
        acc8(a, w3, r3);
        acc8(a, w4, r4);
        acc8(a, w5, r5);
        acc8(a, w6, r6);
        acc8(a, w7, r7);
    }
    for (; e + 6 < end; e += 8) {                 // 4-edge mid-tier
        int s0 = csr_src[e], s1 = csr_src[e + 2], s2 = csr_src[e + 4], s3 = csr_src[e + 6];
        float4 r0 = hrows[s0 * 32 + l32];
        float4 r1 = hrows[s1 * 32 + l32];
        float4 r2 = hrows[s2 * 32 + l32];
        float4 r3 = hrows[s3 * 32 + l32];
        float g0 = l1sh[s0 * 4] + ldh;
        float g1 = l1sh[s1 * 4] + ldh;
        float g2 = l1sh[s2 * 4] + ldh;
        float g3 = l1sh[s3 * 4] + ldh;
        float w0 = __expf(lrelu(g0));
        float w1 = __expf(lrelu(g1));
        float w2 = __expf(lrelu(g2));
        float w3 = __expf(lrelu(g3));
        dn += (w0 + w1) + (w2 + w3);
        acc8(a, w0, r0);
        acc8(a, w1, r1);
        acc8(a, w2, r2);
        acc8(a, w3, r3);
    }
    for (; e < end; e += 2) {
        int s0 = csr_src[e];
        float4 r0 = hrows[s0 * 32 + l32];
        float g0 = l1sh[s0 * 4] + ldh;
        float w0 = __expf(lrelu(g0));
        dn += w0;
        acc8(a, w0, r0);
    }
    // combine the two half-wave edge streams
    #pragma unroll
    for (int j = 0; j < 8; ++j) a[j] += __shfl_xor(a[j], 32, 64);
    dn += __shfl_xor(dn, 32, 64);
    if (half == 0) {
        const float inv = 1.f / (dn + EPSV);
        const float4 bv0 = *(const float4*)(b1 + c8);
        const float4 bv1 = *(const float4*)(b1 + c8 + 4);
        half2_t p01, p23, p45, p67;
        p01[0] = (half_t)fmaxf(fmaf(a[0], inv, bv0.x), 0.f);
        p01[1] = (half_t)fmaxf(fmaf(a[1], inv, bv0.y), 0.f);
        p23[0] = (half_t)fmaxf(fmaf(a[2], inv, bv0.z), 0.f);
        p23[1] = (half_t)fmaxf(fmaf(a[3], inv, bv0.w), 0.f);
        p45[0] = (half_t)fmaxf(fmaf(a[4], inv, bv1.x), 0.f);
        p45[1] = (half_t)fmaxf(fmaf(a[5], inv, bv1.y), 0.f);
        p67[0] = (half_t)fmaxf(fmaf(a[6], inv, bv1.z), 0.f);
        p67[1] = (half_t)fmaxf(fmaf(a[7], inv, bv1.w), 0.f);
        float4 st;
        st.x = __builtin_bit_cast(float, p01);
        st.y = __builtin_bit_cast(float, p23);
        st.z = __builtin_bit_cast(float, p45);
        st.w = __builtin_bit_cast(float, p67);
        *(float4*)(out1h + (size_t)n * C1 + c8) = st;
    }
}

// ---------------- GEMM2 (MFMA fp16): h2 = out1 @ W2, 32x64 tile, K=256; fused logit2 ----------------
#define XS2_LD 264
#define HS2_LD 72
__global__ __launch_bounds__(256) void k_gemm2(
    const half_t* __restrict__ out1h, const half_t* __restrict__ W2T,
    const float* __restrict__ a_s2, const float* __restrict__ a_d2,
    half_t* __restrict__ h2h, float* __restrict__ l2s, float* __restrict__ l2d) {
    __shared__ half_t xs[32 * XS2_LD];            // 16.9 KB
    __shared__ half_t hs[32 * HS2_LD];            // 4.6 KB
    const int base = blockIdx.x * 32;
    const int rows = min(32, N_NODES - base);
    const int tid = threadIdx.x;
    for (int idx = tid; idx < 32 * 32; idx += 256) {
        int row = idx >> 5, c8 = (idx & 31) * 8;
        half8_t hv = {0, 0, 0, 0, 0, 0, 0, 0};
        if (row < rows) hv = *(const half8_t*)(out1h + (size_t)(base + row) * C1 + c8);
        *(half8_t*)(xs + row * XS2_LD + c8) = hv;
    }
    __syncthreads();
    const int lane = tid & 63;
    const int w = tid >> 6;                       // wave w -> cols 16w..16w+15
    const int lr = lane & 15;
    const int lg = lane >> 4;
    f32x4 acc0, acc1;
    #pragma unroll
    for (int r = 0; r < 4; ++r) { acc0[r] = 0.f; acc1[r] = 0.f; }
    #pragma unroll
    for (int kt = 0; kt < 8; ++kt) {
        const int k0 = kt * 32 + lg * 8;
        half8_t A0 = *(const half8_t*)(xs + lr * XS2_LD + k0);
        half8_t A1 = *(const half8_t*)(xs + (16 + lr) * XS2_LD + k0);
        half8_t B  = *(const half8_t*)(W2T + (size_t)(w * 16 + lr) * C1 + k0);
        acc0 = __builtin_amdgcn_mfma_f32_16x16x32_f16(A0, B, acc0, 0, 0, 0);
        acc1 = __builtin_amdgcn_mfma_f32_16x16x32_f16(A1, B, acc1, 0, 0, 0);
    }
    #pragma unroll
    for (int r = 0; r < 4; ++r) {
        hs[(lg * 4 + r) * HS2_LD + w * 16 + lr] = (half_t)acc0[r];
        hs[(16 + lg * 4 + r) * HS2_LD + w * 16 + lr] = (half_t)acc1[r];
    }
    __syncthreads();
    {
        int idx = tid;                            // 32 rows x 8 chunks == 256
        int row = idx >> 3, c8 = (idx & 7) * 8;
        if (row < rows)
            *(float4*)(h2h + (size_t)(base + row) * HID + c8) = *(const float4*)(hs + row * HS2_LD + c8);
    }
    // fused logit2: wave w handles rows w*8..w*8+7; lane covers one channel
    {
        const float vas = a_s2[lane];
        const float vad = a_d2[lane];
        #pragma unroll
        for (int i = 0; i < 8; ++i) {
            int row = w * 8 + i;
            if (row < rows) {
                float v = (float)hs[row * HS2_LD + lane];
                float ps = v * vas, pd = v * vad;
                #pragma unroll
                for (int d = 1; d < 64; d <<= 1) {
                    ps += __shfl_xor(ps, d, 64);
                    pd += __shfl_xor(pd, d, 64);
                }
                if (lane == 0) { l2s[base + row] = ps; l2d[base + row] = pd; }
            }
        }
    }
}

// ---------------- agg2 + final linear: quarter-wave per edge, no max pass ----------------
__global__ __launch_bounds__(256) void k_agg2(
    const half_t* __restrict__ h2h, const float* __restrict__ l2s, const float* __restrict__ l2d,
    const int* __restrict__ rowptr, const int* __restrict__ csr_src,
    const float* __restrict__ b2, const float* __restrict__ Wl, const float* __restrict__ bl,
    float* __restrict__ out) {
    __shared__ float Wls[HID * OUT_CH];           // 16 KB
    __shared__ float vsh[4][HID];
    const int tid = threadIdx.x;
    const int lane = tid & 63;
    const int wv = tid >> 6;
    for (int i = tid; i < HID * OUT_CH; i += 256) Wls[i] = Wl[i];
    const int n = blockIdx.x * 4 + wv;
    const bool active = (n < N_NODES);
    if (active) {
        const int beg = rowptr[n], end = rowptr[n + 1];
        const float ld = l2d[n];
        const int q = lane >> 4;                  // edge stream 0..3
        const int l16 = lane & 15;                // float2 index within row
        const float2* h2rows = (const float2*)h2h;  // 16 float2 per row
        float a0 = 0.f, a1 = 0.f, a2 = 0.f, a3 = 0.f, dn = 0.f;
        int e = beg + q;
        for (; e + 12 < end; e += 16) {           // 4 edges per quarter-wave in flight
            int s0 = csr_src[e], s1 = csr_src[e + 4], s2 = csr_src[e + 8], s3 = csr_src[e + 12];
            float2 v0 = h2rows[s0 * 16 + l16];
            float2 v1 = h2rows[s1 * 16 + l16];
            float2 v2 = h2rows[s2 * 16 + l16];
            float2 v3 = h2rows[s3 * 16 + l16];
            float g0 = l2s[s0] + ld;
            float g1 = l2s[s1] + ld;
            float g2 = l2s[s2] + ld;
            float g3 = l2s[s3] + ld;
            float w0 = __expf(lrelu(g0));
            float w1 = __expf(lrelu(g1));
            float w2 = __expf(lrelu(g2));
            float w3 = __expf(lrelu(g3));
            dn += (w0 + w1) + (w2 + w3);
            half2_t p;
            p = __builtin_bit_cast(half2_t, v0.x); a0 = fmaf(w0, (float)p[0], a0); a1 = fmaf(w0, (float)p[1], a1);
            p = __builtin_bit_cast(half2_t, v0.y); a2 = fmaf(w0, (float)p[0], a2); a3 = fmaf(w0, (float)p[1], a3);
            p = __builtin_bit_cast(half2_t, v1.x); a0 = fmaf(w1, (float)p[0], a0); a1 = fmaf(w1, (float)p[1], a1);
            p = __builtin_bit_cast(half2_t, v1.y); a2 = fmaf(w1, (float)p[0], a2); a3 = fmaf(w1, (float)p[1], a3);
            p = __builtin_bit_cast(half2_t, v2.x); a0 = fmaf(w2, (float)p[0], a0); a1 = fmaf(w2, (float)p[1], a1);
            p = __builtin_bit_cast(half2_t, v2.y); a2 = fmaf(w2, (float)p[0], a2); a3 = fmaf(w2, (float)p[1], a3);
            p = __builtin_bit_cast(half2_t, v3.x); a0 = fmaf(w3, (float)p[0], a0); a1 = fmaf(w3, (float)p[1], a1);
            p = __builtin_bit_cast(half2_t, v3.y); a2 = fmaf(w3, (float)p[0], a2); a3 = fmaf(w3, (float)p[1], a3);
        }
        for (; e < end; e += 4) {
            int s = csr_src[e];
            float2 v = h2rows[s * 16 + l16];
            float lg = l2s[s] + ld;
            float w = __expf(lrelu(lg));
            dn += w;
            half2_t p;
            p = __builtin_bit_cast(half2_t, v.x); a0 = fmaf(w, (float)p[0], a0); a1 = fmaf(w, (float)p[1], a1);
            p = __builtin_bit_cast(half2_t, v.y); a2 = fmaf(w, (float)p[0], a2); a3 = fmaf(w, (float)p[1], a3);
        }
        // combine the four quarter-wave edge streams
        a0 += __shfl_xor(a0, 16, 64); a0 += __shfl_xor(a0, 32, 64);
        a1 += __shfl_xor(a1, 16, 64); a1 += __shfl_xor(a1, 32, 64);
        a2 += __shfl_xor(a2, 16, 64); a2 += __shfl_xor(a2, 32, 64);
        a3 += __shfl_xor(a3, 16, 64); a3 += __shfl_xor(a3, 32, 64);
        dn += __shfl_xor(dn, 16, 64); dn += __shfl_xor(dn, 32, 64);
        if (q == 0) {
            const float inv = 1.f / (dn + EPSV);
            const float4 bv = *(const float4*)(b2 + l16 * 4);
            float4 vv;
            vv.x = fmaf(a0, inv, bv.x);
            vv.y = fmaf(a1, inv, bv.y);
            vv.z = fmaf(a2, inv, bv.z);
            vv.w = fmaf(a3, inv, bv.w);
            *(float4*)(&vsh[wv][l16 * 4]) = vv;
        }
    }
    __syncthreads();
    if (active) {
        float o = bl[lane];
        #pragma unroll
        for (int c2 = 0; c2 < HID; ++c2)
            o = fmaf(vsh[wv][c2], Wls[c2 * OUT_CH + lane], o);
        out[(size_t)n * OUT_CH + lane] = o;
    }
}

extern "C" void kernel_launch(void* const* d_in, const int* in_sizes, int n_in,
                              void* d_out, int out_size, void* d_ws, size_t ws_size,
                              hipStream_t stream) {
    const float* x   = (const float*)d_in[0];
    const int*   ei  = (const int*)d_in[1];
    const float* W1  = (const float*)d_in[2];
    const float* as1 = (const float*)d_in[3];
    const float* ad1 = (const float*)d_in[4];
    const float* b1  = (const float*)d_in[5];
    const float* W2  = (const float*)d_in[6];
    const float* as2 = (const float*)d_in[7];
    const float* ad2 = (const float*)d_in[8];
    const float* b2  = (const float*)d_in[9];
    const float* Wl  = (const float*)d_in[10];
    const float* bl  = (const float*)d_in[11];
    float* out = (float*)d_out;

    char* p = (char*)d_ws;
    auto alloc = [&](size_t bytes) {
        char* r = p;
        p += (bytes + 255) & ~(size_t)255;
        return r;
    };
    int* deg      = (int*)alloc((size_t)N_NODES * 4);
    int* rowptr   = (int*)alloc((size_t)(N_NODES + 1) * 4);
    int* erank    = (int*)alloc((size_t)E_TOT * 4);
    int* csr_src  = (int*)alloc((size_t)E_TOT * 4);
    int* bsum     = (int*)alloc(64 * 4);
    half_t* W1T   = (half_t*)alloc((size_t)IN_CH * C1 * 2);
    half_t* W2T   = (half_t*)alloc((size_t)C1 * HID * 2);
    half_t* h1h   = (half_t*)alloc((size_t)N_NODES * C1 * 2);
    float* l1s    = (float*)alloc((size_t)N_NODES * HEADS * 4);
    float* l1d    = (float*)alloc((size_t)N_NODES * HEADS * 4);
    half_t* out1h = (half_t*)alloc((size_t)N_NODES * C1 * 2);
    half_t* h2h   = (half_t*)alloc((size_t)N_NODES * HID * 2);
    float* l2s    = (float*)alloc((size_t)N_NODES * 4);
    float* l2d    = (float*)alloc((size_t)N_NODES * 4);

    (void)hipMemsetAsync(deg, 0, (size_t)N_NODES * 4, stream);
    k_count_prep<<<NPREP + NCNT, 256, 0, stream>>>(ei, deg, erank, W1, W2, W1T, W2T);
    k_bsum<<<NB_SCAN, 256, 0, stream>>>(deg, bsum);
    k_scanf<<<NB_SCAN, 1024, 0, stream>>>(deg, bsum, rowptr);
    k_scatter<<<(E_TOT + 255) / 256, 256, 0, stream>>>(ei, erank, rowptr, csr_src);
    k_gemm1<<<(N_NODES + 31) / 32, 256, 0, stream>>>(x, W1T, as1, ad1, h1h, l1s, l1d);
    k_agg1<<<(N_NODES + 3) / 4, 256, 0, stream>>>(h1h, l1s, l1d, rowptr, csr_src, b1, out1h);
    k_gemm2<<<(N_NODES + 31) / 32, 256, 0, stream>>>(out1h, W2T, as2, ad2, h2h, l2s, l2d);
    k_agg2<<<(N_NODES + 3) / 4, 256, 0, stream>>>(h2h, l2s, l2d, rowptr, csr_src, b2, Wl, bl, out);
}

// Round 11
// 220.768 us; speedup vs baseline: 1.0429x; 1.0429x over previous
//
#include <hip/hip_runtime.h>

#define N_NODES 50000
#define N_EDGES 800000
#define E_TOT   850000            // N_EDGES + N_NODES self loops
#define IN_CH   128
#define HID     64
#define HEADS   4
#define C1      256               // HEADS*HID
#define OUT_CH  64
#define NEG_SLOPE 0.2f
#define EPSV    1e-16f

typedef _Float16 half_t;
typedef _Float16 half2_t __attribute__((ext_vector_type(2)));
typedef _Float16 half8_t __attribute__((ext_vector_type(8)));
typedef float f32x4 __attribute__((ext_vector_type(4)));

__device__ __forceinline__ float lrelu(float v) {
    return (v > 0.f) ? v : NEG_SLOPE * v;
}

__device__ __forceinline__ void acc8(float (&a)[8], float w, float4 r) {
    half2_t p;
    p = __builtin_bit_cast(half2_t, r.x); a[0] = fmaf(w, (float)p[0], a[0]); a[1] = fmaf(w, (float)p[1], a[1]);
    p = __builtin_bit_cast(half2_t, r.y); a[2] = fmaf(w, (float)p[0], a[2]); a[3] = fmaf(w, (float)p[1], a[3]);
    p = __builtin_bit_cast(half2_t, r.z); a[4] = fmaf(w, (float)p[0], a[4]); a[5] = fmaf(w, (float)p[1], a[5]);
    p = __builtin_bit_cast(half2_t, r.w); a[6] = fmaf(w, (float)p[0], a[6]); a[7] = fmaf(w, (float)p[1], a[7]);
}

// ---------------- fused: weight prep (blocks [0,NPREP)) + edge count+rank (rest) ----------------
#define NPREP ((IN_CH * C1 + C1 * HID + 255) / 256)    // 192
#define NCNT  ((E_TOT + 255) / 256)                    // 3321
__global__ __launch_bounds__(256) void k_count_prep(
    const int* __restrict__ ei, int* __restrict__ deg, int* __restrict__ erank,
    const float* __restrict__ W1, const float* __restrict__ W2,
    half_t* __restrict__ W1T, half_t* __restrict__ W2T) {
    const int gb = blockIdx.x;
    const int tid = threadIdx.x;
    if (gb < NPREP) {
        int i = gb * 256 + tid;
        if (i < IN_CH * C1) {
            int c = i >> 7, k = i & 127;
            W1T[i] = (half_t)W1[k * C1 + c];
        }
        int j = i - IN_CH * C1;
        if (j >= 0 && j < C1 * HID) {
            int c = j >> 8, k = j & 255;
            W2T[j] = (half_t)W2[k * HID + c];
        }
    } else {
        int e = (gb - NPREP) * 256 + tid;
        if (e < E_TOT) {
            int d = (e < N_EDGES) ? ei[N_EDGES + e] : (e - N_EDGES);
            erank[e] = atomicAdd(&deg[d], 1);
        }
    }
}

#define SCAN_CH 1024
#define NB_SCAN ((N_NODES + SCAN_CH - 1) / SCAN_CH)   // 49

__global__ __launch_bounds__(256) void k_bsum(const int* __restrict__ deg,
                                              int* __restrict__ bsum) {
    const int b = blockIdx.x;
    const int tid = threadIdx.x;
    int sum = 0;
    for (int i = tid; i < SCAN_CH; i += 256) {
        int idx = b * SCAN_CH + i;
        sum += (idx < N_NODES) ? deg[idx] : 0;
    }
    #pragma unroll
    for (int d = 1; d < 64; d <<= 1) sum += __shfl_xor(sum, d, 64);
    __shared__ int ws[4];
    if ((tid & 63) == 0) ws[tid >> 6] = sum;
    __syncthreads();
    if (tid == 0) bsum[b] = ws[0] + ws[1] + ws[2] + ws[3];
}

// scan with fused block-offset prefix (reads bsum directly)
__global__ __launch_bounds__(1024) void k_scanf(const int* __restrict__ deg,
                                                const int* __restrict__ bsum,
                                                int* __restrict__ rowptr) {
    __shared__ int wsum[16];
    __shared__ int boff_s;
    const int b = blockIdx.x;
    const int tid = threadIdx.x;
    const int lane = tid & 63;
    const int wv = tid >> 6;                      // 16 waves
    if (wv == 0) {                                // block prefix from bsum[0..b)
        int v = (lane < b) ? bsum[lane] : 0;      // b <= 48 < 64
        #pragma unroll
        for (int d = 1; d < 64; d <<= 1) v += __shfl_xor(v, d, 64);
        if (lane == 0) boff_s = v;
    }
    if (b == 0 && tid == 0) rowptr[N_NODES] = E_TOT;
    const int i = b * SCAN_CH + tid;
    int v = (i < N_NODES) ? deg[i] : 0;
    int s = v;
    #pragma unroll
    for (int d = 1; d < 64; d <<= 1) {
        int t = __shfl_up(s, d, 64);
        if (lane >= d) s += t;
    }
    if (lane == 63) wsum[wv] = s;
    __syncthreads();
    if (wv == 0 && lane < 16) {
        int w = wsum[lane];
        #pragma unroll
        for (int d = 1; d < 16; d <<= 1) {
            int t = __shfl_up(w, d, 64);
            if (lane >= d) w += t;
        }
        wsum[lane] = w;
    }
    __syncthreads();
    int excl = boff_s + ((wv > 0) ? wsum[wv - 1] : 0) + (s - v);
    if (i < N_NODES) rowptr[i] = excl;
}

// ---------------- scatter: atomic-free (pos = rowptr[d] + precomputed rank) ----------------
__global__ void k_scatter(const int* __restrict__ ei, const int* __restrict__ erank,
                          const int* __restrict__ rowptr, int* __restrict__ csr_src) {
    int e = blockIdx.x * blockDim.x + threadIdx.x;
    if (e >= E_TOT) return;
    int s, d;
    if (e < N_EDGES) { s = ei[e]; d = ei[N_EDGES + e]; }
    else             { s = d = e - N_EDGES; }
    csr_src[rowptr[d] + erank[e]] = s;
}

// ---------------- GEMM1 (MFMA fp16): h1 = x @ W1, 64x256 tile, K=128; fused logit1 ----------------
// xs (staging, stride 136) and hs (transpose, stride 264) alias one 33.8 KB LDS buffer;
// phases are separated by __syncthreads.
#define XS1_LD 136
#define HS1_LD 264
__global__ __launch_bounds__(256) void k_gemm1(
    const float* __restrict__ x, const half_t* __restrict__ W1T,
    const float* __restrict__ a_s1, const float* __restrict__ a_d1,
    half_t* __restrict__ h1h, float* __restrict__ l1s, float* __restrict__ l1d) {
    __shared__ half_t sbuf[64 * HS1_LD];          // 33.8 KB
    const int base = blockIdx.x * 64;
    const int rows = min(64, N_NODES - base);
    const int tid = threadIdx.x;
    // stage x tile as fp16 (stride XS1_LD)
    for (int idx = tid; idx < 64 * 16; idx += 256) {
        int row = idx >> 4, c8 = (idx & 15) * 8;
        half8_t hv = {0, 0, 0, 0, 0, 0, 0, 0};
        if (row < rows) {
            const float4 v0 = *(const float4*)(x + (size_t)(base + row) * IN_CH + c8);
            const float4 v1 = *(const float4*)(x + (size_t)(base + row) * IN_CH + c8 + 4);
            hv[0] = (half_t)v0.x; hv[1] = (half_t)v0.y; hv[2] = (half_t)v0.z; hv[3] = (half_t)v0.w;
            hv[4] = (half_t)v1.x; hv[5] = (half_t)v1.y; hv[6] = (half_t)v1.z; hv[7] = (half_t)v1.w;
        }
        *(half8_t*)(sbuf + row * XS1_LD + c8) = hv;
    }
    __syncthreads();
    const int lane = tid & 63;
    const int w = tid >> 6;
    const int cw = w * 64;                        // wave's 64-col slice
    const int lr = lane & 15;
    const int lg = lane >> 4;
    f32x4 acc[4][4];                              // [row-tile][col-tile]
    #pragma unroll
    for (int i = 0; i < 4; ++i)
        #pragma unroll
        for (int j = 0; j < 4; ++j)
            #pragma unroll
            for (int r = 0; r < 4; ++r) acc[i][j][r] = 0.f;

    #pragma unroll
    for (int kt = 0; kt < 4; ++kt) {
        const int k0 = kt * 32 + lg * 8;
        half8_t A[4];
        #pragma unroll
        for (int rt = 0; rt < 4; ++rt)
            A[rt] = *(const half8_t*)(sbuf + (rt * 16 + lr) * XS1_LD + k0);
        #pragma unroll
        for (int ct = 0; ct < 4; ++ct) {
            half8_t B = *(const half8_t*)(W1T + (size_t)(cw + ct * 16 + lr) * IN_CH + k0);
            #pragma unroll
            for (int rt = 0; rt < 4; ++rt)
                acc[rt][ct] = __builtin_amdgcn_mfma_f32_16x16x32_f16(A[rt], B, acc[rt][ct], 0, 0, 0);
        }
    }
    __syncthreads();                              // before clobbering xs region with hs
    // C layout: col = lane&15, row = (lane>>4)*4 + r  -> LDS transpose, coalesced store
    #pragma unroll
    for (int rt = 0; rt < 4; ++rt)
        #pragma unroll
        for (int ct = 0; ct < 4; ++ct)
            #pragma unroll
            for (int r = 0; r < 4; ++r)
                sbuf[(rt * 16 + lg * 4 + r) * HS1_LD + cw + ct * 16 + lr] = (half_t)acc[rt][ct][r];
    __syncthreads();
    for (int idx = tid; idx < 64 * 32; idx += 256) {
        int row = idx >> 5, c8 = (idx & 31) * 8;
        if (row < rows)
            *(float4*)(h1h + (size_t)(base + row) * C1 + c8) = *(const float4*)(sbuf + row * HS1_LD + c8);
    }
    // fused logit1: wave w handles rows w*16..w*16+15; lane covers ch lane*4..+3
    {
        const int c4l = lane * 4;
        const float4 av = *(const float4*)(a_s1 + c4l);
        const float4 dv = *(const float4*)(a_d1 + c4l);
        #pragma unroll
        for (int i = 0; i < 16; ++i) {
            int row = w * 16 + i;
            if (row < rows) {
                float2 rr = *(const float2*)(sbuf + row * HS1_LD + c4l);
                half2_t ha = __builtin_bit_cast(half2_t, rr.x);
                half2_t hb = __builtin_bit_cast(half2_t, rr.y);
                float ps = (float)ha[0] * av.x + (float)ha[1] * av.y + (float)hb[0] * av.z + (float)hb[1] * av.w;
                float pd = (float)ha[0] * dv.x + (float)ha[1] * dv.y + (float)hb[0] * dv.z + (float)hb[1] * dv.w;
                #pragma unroll
                for (int d = 1; d < 16; d <<= 1) {
                    ps += __shfl_xor(ps, d, 64);
                    pd += __shfl_xor(pd, d, 64);
                }
                if ((lane & 15) == 0) {
                    int hh = lane >> 4;
                    l1s[(base + row) * HEADS + hh] = ps;
                    l1d[(base + row) * HEADS + hh] = pd;
                }
            }
        }
    }
}

// ---------------- agg1: half-wave per edge, 8 fp16 ch/lane (16B loads), 4-deep unroll ----------------
__global__ __launch_bounds__(256) void k_agg1(
    const half_t* __restrict__ h1h, const float* __restrict__ l1s, const float* __restrict__ l1d,
    const int* __restrict__ rowptr, const int* __restrict__ csr_src,
    const float* __restrict__ b1, half_t* __restrict__ out1h) {
    const int tid = threadIdx.x;
    const int lane = tid & 63;
    const int wv = tid >> 6;
    const int n = blockIdx.x * 4 + wv;
    if (n >= N_NODES) return;                     // no syncthreads below
    const int beg = rowptr[n], end = rowptr[n + 1];
    const float4 ldv = *(const float4*)(l1d + (size_t)n * 4);
    const int half = lane >> 5;                   // edge stream 0/1
    const int l32 = lane & 31;
    const int c8 = l32 * 8;                       // this lane's 8 channels
    const int hh = l32 >> 3;                      // head of those channels
    const float ldh = (hh & 2) ? ((hh & 1) ? ldv.w : ldv.z) : ((hh & 1) ? ldv.y : ldv.x);
    const float* l1sh = l1s + hh;
    const float4* hrows = (const float4*)h1h;     // 32 float4 per row
    float a[8] = {0.f, 0.f, 0.f, 0.f, 0.f, 0.f, 0.f, 0.f};
    float dn = 0.f;
    int e = beg + half;
    for (; e + 6 < end; e += 8) {                 // 4 edges per half-wave in flight
        int s0 = csr_src[e], s1 = csr_src[e + 2], s2 = csr_src[e + 4], s3 = csr_src[e + 6];
        float4 r0 = hrows[s0 * 32 + l32];
        float4 r1 = hrows[s1 * 32 + l32];
        float4 r2 = hrows[s2 * 32 + l32];
        float4 r3 = hrows[s3 * 32 + l32];
        float g0 = l1sh[s0 * 4] + ldh;
        float g1 = l1sh[s1 * 4] + ldh;
        float g2 = l1sh[s2 * 4] + ldh;
        float g3 = l1sh[s3 * 4] + ldh;
        float w0 = __expf(lrelu(g0));
        float w1 = __expf(lrelu(g1));
        float w2 = __expf(lrelu(g2));
        float w3 = __expf(lrelu(g3));
        dn += (w0 + w1) + (w2 + w3);
        acc8(a, w0, r0);
        acc8(a, w1, r1);
        acc8(a, w2, r2);
        acc8(a, w3, r3);
    }
    for (; e < end; e += 2) {
        int s0 = csr_src[e];
        float4 r0 = hrows[s0 * 32 + l32];
        float g0 = l1sh[s0 * 4] + ldh;
        float w0 = __expf(lrelu(g0));
        dn += w0;
        acc8(a, w0, r0);
    }
    // combine the two half-wave edge streams
    #pragma unroll
    for (int j = 0; j < 8; ++j) a[j] += __shfl_xor(a[j], 32, 64);
    dn += __shfl_xor(dn, 32, 64);
    if (half == 0) {
        const float inv = 1.f / (dn + EPSV);
        const float4 bv0 = *(const float4*)(b1 + c8);
        const float4 bv1 = *(const float4*)(b1 + c8 + 4);
        half2_t p01, p23, p45, p67;
        p01[0] = (half_t)fmaxf(fmaf(a[0], inv, bv0.x), 0.f);
        p01[1] = (half_t)fmaxf(fmaf(a[1], inv, bv0.y), 0.f);
        p23[0] = (half_t)fmaxf(fmaf(a[2], inv, bv0.z), 0.f);
        p23[1] = (half_t)fmaxf(fmaf(a[3], inv, bv0.w), 0.f);
        p45[0] = (half_t)fmaxf(fmaf(a[4], inv, bv1.x), 0.f);
        p45[1] = (half_t)fmaxf(fmaf(a[5], inv, bv1.y), 0.f);
        p67[0] = (half_t)fmaxf(fmaf(a[6], inv, bv1.z), 0.f);
        p67[1] = (half_t)fmaxf(fmaf(a[7], inv, bv1.w), 0.f);
        float4 st;
        st.x = __builtin_bit_cast(float, p01);
        st.y = __builtin_bit_cast(float, p23);
        st.z = __builtin_bit_cast(float, p45);
        st.w = __builtin_bit_cast(float, p67);
        *(float4*)(out1h + (size_t)n * C1 + c8) = st;
    }
}

// ---------------- GEMM2 (MFMA fp16): h2 = out1 @ W2, 32x64 tile, K=256; fused logit2 ----------------
#define XS2_LD 264
#define HS2_LD 72
__global__ __launch_bounds__(256) void k_gemm2(
    const half_t* __restrict__ out1h, const half_t* __restrict__ W2T,
    const float* __restrict__ a_s2, const float* __restrict__ a_d2,
    half_t* __restrict__ h2h, float* __restrict__ l2s, float* __restrict__ l2d) {
    __shared__ half_t xs[32 * XS2_LD];            // 16.9 KB
    __shared__ half_t hs[32 * HS2_LD];            // 4.6 KB
    const int base = blockIdx.x * 32;
    const int rows = min(32, N_NODES - base);
    const int tid = threadIdx.x;
    for (int idx = tid; idx < 32 * 32; idx += 256) {
        int row = idx >> 5, c8 = (idx & 31) * 8;
        half8_t hv = {0, 0, 0, 0, 0, 0, 0, 0};
        if (row < rows) hv = *(const half8_t*)(out1h + (size_t)(base + row) * C1 + c8);
        *(half8_t*)(xs + row * XS2_LD + c8) = hv;
    }
    __syncthreads();
    const int lane = tid & 63;
    const int w = tid >> 6;                       // wave w -> cols 16w..16w+15
    const int lr = lane & 15;
    const int lg = lane >> 4;
    f32x4 acc0, acc1;
    #pragma unroll
    for (int r = 0; r < 4; ++r) { acc0[r] = 0.f; acc1[r] = 0.f; }
    #pragma unroll
    for (int kt = 0; kt < 8; ++kt) {
        const int k0 = kt * 32 + lg * 8;
        half8_t A0 = *(const half8_t*)(xs + lr * XS2_LD + k0);
        half8_t A1 = *(const half8_t*)(xs + (16 + lr) * XS2_LD + k0);
        half8_t B  = *(const half8_t*)(W2T + (size_t)(w * 16 + lr) * C1 + k0);
        acc0 = __builtin_amdgcn_mfma_f32_16x16x32_f16(A0, B, acc0, 0, 0, 0);
        acc1 = __builtin_amdgcn_mfma_f32_16x16x32_f16(A1, B, acc1, 0, 0, 0);
    }
    #pragma unroll
    for (int r = 0; r < 4; ++r) {
        hs[(lg * 4 + r) * HS2_LD + w * 16 + lr] = (half_t)acc0[r];
        hs[(16 + lg * 4 + r) * HS2_LD + w * 16 + lr] = (half_t)acc1[r];
    }
    __syncthreads();
    {
        int idx = tid;                            // 32 rows x 8 chunks == 256
        int row = idx >> 3, c8 = (idx & 7) * 8;
        if (row < rows)
            *(float4*)(h2h + (size_t)(base + row) * HID + c8) = *(const float4*)(hs + row * HS2_LD + c8);
    }
    // fused logit2: wave w handles rows w*8..w*8+7; lane covers one channel
    {
        const float vas = a_s2[lane];
        const float vad = a_d2[lane];
        #pragma unroll
        for (int i = 0; i < 8; ++i) {
            int row = w * 8 + i;
            if (row < rows) {
                float v = (float)hs[row * HS2_LD + lane];
                float ps = v * vas, pd = v * vad;
                #pragma unroll
                for (int d = 1; d < 64; d <<= 1) {
                    ps += __shfl_xor(ps, d, 64);
                    pd += __shfl_xor(pd, d, 64);
                }
                if (lane == 0) { l2s[base + row] = ps; l2d[base + row] = pd; }
            }
        }
    }
}

// ---------------- agg2 + final linear: quarter-wave per edge, no max pass ----------------
__global__ __launch_bounds__(256) void k_agg2(
    const half_t* __restrict__ h2h, const float* __restrict__ l2s, const float* __restrict__ l2d,
    const int* __restrict__ rowptr, const int* __restrict__ csr_src,
    const float* __restrict__ b2, const float* __restrict__ Wl, const float* __restrict__ bl,
    float* __restrict__ out) {
    __shared__ float Wls[HID * OUT_CH];           // 16 KB
    __shared__ float vsh[4][HID];
    const int tid = threadIdx.x;
    const int lane = tid & 63;
    const int wv = tid >> 6;
    for (int i = tid; i < HID * OUT_CH; i += 256) Wls[i] = Wl[i];
    const int n = blockIdx.x * 4 + wv;
    const bool active = (n < N_NODES);
    if (active) {
        const int beg = rowptr[n], end = rowptr[n + 1];
        const float ld = l2d[n];
        const int q = lane >> 4;                  // edge stream 0..3
        const int l16 = lane & 15;                // float2 index within row
        const float2* h2rows = (const float2*)h2h;  // 16 float2 per row
        float a0 = 0.f, a1 = 0.f, a2 = 0.f, a3 = 0.f, dn = 0.f;
        int e = beg + q;
        for (; e + 12 < end; e += 16) {           // 4 edges per quarter-wave in flight
            int s0 = csr_src[e], s1 = csr_src[e + 4], s2 = csr_src[e + 8], s3 = csr_src[e + 12];
            float2 v0 = h2rows[s0 * 16 + l16];
            float2 v1 = h2rows[s1 * 16 + l16];
            float2 v2 = h2rows[s2 * 16 + l16];
            float2 v3 = h2rows[s3 * 16 + l16];
            float g0 = l2s[s0] + ld;
            float g1 = l2s[s1] + ld;
            float g2 = l2s[s2] + ld;
            float g3 = l2s[s3] + ld;
            float w0 = __expf(lrelu(g0));
            float w1 = __expf(lrelu(g1));
            float w2 = __expf(lrelu(g2));
            float w3 = __expf(lrelu(g3));
            dn += (w0 + w1) + (w2 + w3);
            half2_t p;
            p = __builtin_bit_cast(half2_t, v0.x); a0 = fmaf(w0, (float)p[0], a0); a1 = fmaf(w0, (float)p[1], a1);
            p = __builtin_bit_cast(half2_t, v0.y); a2 = fmaf(w0, (float)p[0], a2); a3 = fmaf(w0, (float)p[1], a3);
            p = __builtin_bit_cast(half2_t, v1.x); a0 = fmaf(w1, (float)p[0], a0); a1 = fmaf(w1, (float)p[1], a1);
            p = __builtin_bit_cast(half2_t, v1.y); a2 = fmaf(w1, (float)p[0], a2); a3 = fmaf(w1, (float)p[1], a3);
            p = __builtin_bit_cast(half2_t, v2.x); a0 = fmaf(w2, (float)p[0], a0); a1 = fmaf(w2, (float)p[1], a1);
            p = __builtin_bit_cast(half2_t, v2.y); a2 = fmaf(w2, (float)p[0], a2); a3 = fmaf(w2, (float)p[1], a3);
            p = __builtin_bit_cast(half2_t, v3.x); a0 = fmaf(w3, (float)p[0], a0); a1 = fmaf(w3, (float)p[1], a1);
            p = __builtin_bit_cast(half2_t, v3.y); a2 = fmaf(w3, (float)p[0], a2); a3 = fmaf(w3, (float)p[1], a3);
        }
        for (; e < end; e += 4) {
            int s = csr_src[e];
            float2 v = h2rows[s * 16 + l16];
            float lg = l2s[s] + ld;
            float w = __expf(lrelu(lg));
            dn += w;
            half2_t p;
            p = __builtin_bit_cast(half2_t, v.x); a0 = fmaf(w, (float)p[0], a0); a1 = fmaf(w, (float)p[1], a1);
            p = __builtin_bit_cast(half2_t, v.y); a2 = fmaf(w, (float)p[0], a2); a3 = fmaf(w, (float)p[1], a3);
        }
        // combine the four quarter-wave edge streams
        a0 += __shfl_xor(a0, 16, 64); a0 += __shfl_xor(a0, 32, 64);
        a1 += __shfl_xor(a1, 16, 64); a1 += __shfl_xor(a1, 32, 64);
        a2 += __shfl_xor(a2, 16, 64); a2 += __shfl_xor(a2, 32, 64);
        a3 += __shfl_xor(a3, 16, 64); a3 += __shfl_xor(a3, 32, 64);
        dn += __shfl_xor(dn, 16, 64); dn += __shfl_xor(dn, 32, 64);
        if (q == 0) {
            const float inv = 1.f / (dn + EPSV);
            const float4 bv = *(const float4*)(b2 + l16 * 4);
            float4 vv;
            vv.x = fmaf(a0, inv, bv.x);
            vv.y = fmaf(a1, inv, bv.y);
            vv.z = fmaf(a2, inv, bv.z);
            vv.w = fmaf(a3, inv, bv.w);
            *(float4*)(&vsh[wv][l16 * 4]) = vv;
        }
    }
    __syncthreads();
    if (active) {
        float o = bl[lane];
        #pragma unroll
        for (int c2 = 0; c2 < HID; ++c2)
            o = fmaf(vsh[wv][c2], Wls[c2 * OUT_CH + lane], o);
        out[(size_t)n * OUT_CH + lane] = o;
    }
}

extern "C" void kernel_launch(void* const* d_in, const int* in_sizes, int n_in,
                              void* d_out, int out_size, void* d_ws, size_t ws_size,
                              hipStream_t stream) {
    const float* x   = (const float*)d_in[0];
    const int*   ei  = (const int*)d_in[1];
    const float* W1  = (const float*)d_in[2];
    const float* as1 = (const float*)d_in[3];
    const float* ad1 = (const float*)d_in[4];
    const float* b1  = (const float*)d_in[5];
    const float* W2  = (const float*)d_in[6];
    const float* as2 = (const float*)d_in[7];
    const float* ad2 = (const float*)d_in[8];
    const float* b2  = (const float*)d_in[9];
    const float* Wl  = (const float*)d_in[10];
    const float* bl  = (const float*)d_in[11];
    float* out = (float*)d_out;

    char* p = (char*)d_ws;
    auto alloc = [&](size_t bytes) {
        char* r = p;
        p += (bytes + 255) & ~(size_t)255;
        return r;
    };
    int* deg      = (int*)alloc((size_t)N_NODES * 4);
    int* rowptr   = (int*)alloc((size_t)(N_NODES + 1) * 4);
    int* erank    = (int*)alloc((size_t)E_TOT * 4);
    int* csr_src  = (int*)alloc((size_t)E_TOT * 4);
    int* bsum     = (int*)alloc(64 * 4);
    half_t* W1T   = (half_t*)alloc((size_t)IN_CH * C1 * 2);
    half_t* W2T   = (half_t*)alloc((size_t)C1 * HID * 2);
    half_t* h1h   = (half_t*)alloc((size_t)N_NODES * C1 * 2);
    float* l1s    = (float*)alloc((size_t)N_NODES * HEADS * 4);
    float* l1d    = (float*)alloc((size_t)N_NODES * HEADS * 4);
    half_t* out1h = (half_t*)alloc((size_t)N_NODES * C1 * 2);
    half_t* h2h   = (half_t*)alloc((size_t)N_NODES * HID * 2);
    float* l2s    = (float*)alloc((size_t)N_NODES * 4);
    float* l2d    = (float*)alloc((size_t)N_NODES * 4);

    (void)hipMemsetAsync(deg, 0, (size_t)N_NODES * 4, stream);
    k_count_prep<<<NPREP + NCNT, 256, 0, stream>>>(ei, deg, erank, W1, W2, W1T, W2T);
    k_bsum<<<NB_SCAN, 256, 0, stream>>>(deg, bsum);
    k_scanf<<<NB_SCAN, 1024, 0, stream>>>(deg, bsum, rowptr);
    k_scatter<<<(E_TOT + 255) / 256, 256, 0, stream>>>(ei, erank, rowptr, csr_src);
    k_gemm1<<<(N_NODES + 63) / 64, 256, 0, stream>>>(x, W1T, as1, ad1, h1h, l1s, l1d);
    k_agg1<<<(N_NODES + 3) / 4, 256, 0, stream>>>(h1h, l1s, l1d, rowptr, csr_src, b1, out1h);
    k_gemm2<<<(N_NODES + 31) / 32, 256, 0, stream>>>(out1h, W2T, as2, ad2, h2h, l2s, l2d);
    k_agg2<<<(N_NODES + 3) / 4, 256, 0, stream>>>(h2h, l2s, l2d, rowptr, csr_src, b2, Wl, bl, out);
}

// Round 12
// 215.769 us; speedup vs baseline: 1.0671x; 1.0232x over previous
//
#include <hip/hip_runtime.h>

#define N_NODES 50000
#define N_EDGES 800000
#define E_TOT   850000            // N_EDGES + N_NODES self loops
#define IN_CH   128
#define HID     64
#define HEADS   4
#define C1      256               // HEADS*HID
#define OUT_CH  64
#define NEG_SLOPE 0.2f
#define EPSV    1e-16f

typedef _Float16 half_t;
typedef _Float16 half2_t __attribute__((ext_vector_type(2)));
typedef _Float16 half8_t __attribute__((ext_vector_type(8)));
typedef float f32x4 __attribute__((ext_vector_type(4)));

__device__ __forceinline__ float lrelu(float v) {
    return (v > 0.f) ? v : NEG_SLOPE * v;
}

__device__ __forceinline__ void acc8(float (&a)[8], float w, float4 r) {
    half2_t p;
    p = __builtin_bit_cast(half2_t, r.x); a[0] = fmaf(w, (float)p[0], a[0]); a[1] = fmaf(w, (float)p[1], a[1]);
    p = __builtin_bit_cast(half2_t, r.y); a[2] = fmaf(w, (float)p[0], a[2]); a[3] = fmaf(w, (float)p[1], a[3]);
    p = __builtin_bit_cast(half2_t, r.z); a[4] = fmaf(w, (float)p[0], a[4]); a[5] = fmaf(w, (float)p[1], a[5]);
    p = __builtin_bit_cast(half2_t, r.w); a[6] = fmaf(w, (float)p[0], a[6]); a[7] = fmaf(w, (float)p[1], a[7]);
}

// ---- fused: weight prep [0,NPREP) + x->fp16 convert [NPREP,NPREP+NXC) + edge count+rank (rest) ----
#define NPREP ((IN_CH * C1 + C1 * HID + 255) / 256)      // 192
#define NXC   ((N_NODES * IN_CH / 8 + 255) / 256)        // 3125
#define NCNT  ((E_TOT + 255) / 256)                      // 3321
__global__ __launch_bounds__(256) void k_count_prep(
    const int* __restrict__ ei, int* __restrict__ deg, int* __restrict__ erank,
    const float* __restrict__ W1, const float* __restrict__ W2,
    const float* __restrict__ x,
    half_t* __restrict__ W1T, half_t* __restrict__ W2T, half_t* __restrict__ xh) {
    const int gb = blockIdx.x;
    const int tid = threadIdx.x;
    if (gb < NPREP) {
        int i = gb * 256 + tid;
        if (i < IN_CH * C1) {
            int c = i >> 7, k = i & 127;
            W1T[i] = (half_t)W1[k * C1 + c];
        }
        int j = i - IN_CH * C1;
        if (j >= 0 && j < C1 * HID) {
            int c = j >> 8, k = j & 255;
            W2T[j] = (half_t)W2[k * HID + c];
        }
    } else if (gb < NPREP + NXC) {
        int i = (gb - NPREP) * 256 + tid;                // one half8 per thread
        if (i < N_NODES * IN_CH / 8) {
            const float4 v0 = *(const float4*)(x + (size_t)i * 8);
            const float4 v1 = *(const float4*)(x + (size_t)i * 8 + 4);
            half8_t hv;
            hv[0] = (half_t)v0.x; hv[1] = (half_t)v0.y; hv[2] = (half_t)v0.z; hv[3] = (half_t)v0.w;
            hv[4] = (half_t)v1.x; hv[5] = (half_t)v1.y; hv[6] = (half_t)v1.z; hv[7] = (half_t)v1.w;
            *(half8_t*)(xh + (size_t)i * 8) = hv;
        }
    } else {
        int e = (gb - NPREP - NXC) * 256 + tid;
        if (e < E_TOT) {
            int d = (e < N_EDGES) ? ei[N_EDGES + e] : (e - N_EDGES);
            erank[e] = atomicAdd(&deg[d], 1);
        }
    }
}

#define SCAN_CH 1024
#define NB_SCAN ((N_NODES + SCAN_CH - 1) / SCAN_CH)   // 49

__global__ __launch_bounds__(256) void k_bsum(const int* __restrict__ deg,
                                              int* __restrict__ bsum) {
    const int b = blockIdx.x;
    const int tid = threadIdx.x;
    int sum = 0;
    for (int i = tid; i < SCAN_CH; i += 256) {
        int idx = b * SCAN_CH + i;
        sum += (idx < N_NODES) ? deg[idx] : 0;
    }
    #pragma unroll
    for (int d = 1; d < 64; d <<= 1) sum += __shfl_xor(sum, d, 64);
    __shared__ int ws[4];
    if ((tid & 63) == 0) ws[tid >> 6] = sum;
    __syncthreads();
    if (tid == 0) bsum[b] = ws[0] + ws[1] + ws[2] + ws[3];
}

// scan with fused block-offset prefix (reads bsum directly)
__global__ __launch_bounds__(1024) void k_scanf(const int* __restrict__ deg,
                                                const int* __restrict__ bsum,
                                                int* __restrict__ rowptr) {
    __shared__ int wsum[16];
    __shared__ int boff_s;
    const int b = blockIdx.x;
    const int tid = threadIdx.x;
    const int lane = tid & 63;
    const int wv = tid >> 6;                      // 16 waves
    if (wv == 0) {                                // block prefix from bsum[0..b)
        int v = (lane < b) ? bsum[lane] : 0;      // b <= 48 < 64
        #pragma unroll
        for (int d = 1; d < 64; d <<= 1) v += __shfl_xor(v, d, 64);
        if (lane == 0) boff_s = v;
    }
    if (b == 0 && tid == 0) rowptr[N_NODES] = E_TOT;
    const int i = b * SCAN_CH + tid;
    int v = (i < N_NODES) ? deg[i] : 0;
    int s = v;
    #pragma unroll
    for (int d = 1; d < 64; d <<= 1) {
        int t = __shfl_up(s, d, 64);
        if (lane >= d) s += t;
    }
    if (lane == 63) wsum[wv] = s;
    __syncthreads();
    if (wv == 0 && lane < 16) {
        int w = wsum[lane];
        #pragma unroll
        for (int d = 1; d < 16; d <<= 1) {
            int t = __shfl_up(w, d, 64);
            if (lane >= d) w += t;
        }
        wsum[lane] = w;
    }
    __syncthreads();
    int excl = boff_s + ((wv > 0) ? wsum[wv - 1] : 0) + (s - v);
    if (i < N_NODES) rowptr[i] = excl;
}

// ---------------- scatter: atomic-free (pos = rowptr[d] + precomputed rank) ----------------
__global__ void k_scatter(const int* __restrict__ ei, const int* __restrict__ erank,
                          const int* __restrict__ rowptr, int* __restrict__ csr_src) {
    int e = blockIdx.x * blockDim.x + threadIdx.x;
    if (e >= E_TOT) return;
    int s, d;
    if (e < N_EDGES) { s = ei[e]; d = ei[N_EDGES + e]; }
    else             { s = d = e - N_EDGES; }
    csr_src[rowptr[d] + erank[e]] = s;
}

// ---------------- GEMM1 (MFMA fp16): h1 = xh @ W1, 64x256 tile, K=128; fused logit1 ----------------
#define XS1_LD 136
#define HS1_LD 264
__global__ __launch_bounds__(256) void k_gemm1(
    const half_t* __restrict__ xh, const half_t* __restrict__ W1T,
    const float* __restrict__ a_s1, const float* __restrict__ a_d1,
    half_t* __restrict__ h1h, float* __restrict__ l1s, float* __restrict__ l1d) {
    __shared__ half_t sbuf[64 * HS1_LD];          // 33.8 KB (xs and hs alias)
    const int base = blockIdx.x * 64;
    const int rows = min(64, N_NODES - base);
    const int tid = threadIdx.x;
    // stage xh tile (stride XS1_LD)
    for (int idx = tid; idx < 64 * 16; idx += 256) {
        int row = idx >> 4, c8 = (idx & 15) * 8;
        half8_t hv = {0, 0, 0, 0, 0, 0, 0, 0};
        if (row < rows) hv = *(const half8_t*)(xh + (size_t)(base + row) * IN_CH + c8);
        *(half8_t*)(sbuf + row * XS1_LD + c8) = hv;
    }
    __syncthreads();
    const int lane = tid & 63;
    const int w = tid >> 6;
    const int cw = w * 64;                        // wave's 64-col slice
    const int lr = lane & 15;
    const int lg = lane >> 4;
    f32x4 acc[4][4];                              // [row-tile][col-tile]
    #pragma unroll
    for (int i = 0; i < 4; ++i)
        #pragma unroll
        for (int j = 0; j < 4; ++j)
            #pragma unroll
            for (int r = 0; r < 4; ++r) acc[i][j][r] = 0.f;

    #pragma unroll
    for (int kt = 0; kt < 4; ++kt) {
        const int k0 = kt * 32 + lg * 8;
        half8_t A[4];
        #pragma unroll
        for (int rt = 0; rt < 4; ++rt)
            A[rt] = *(const half8_t*)(sbuf + (rt * 16 + lr) * XS1_LD + k0);
        #pragma unroll
        for (int ct = 0; ct < 4; ++ct) {
            half8_t B = *(const half8_t*)(W1T + (size_t)(cw + ct * 16 + lr) * IN_CH + k0);
            #pragma unroll
            for (int rt = 0; rt < 4; ++rt)
                acc[rt][ct] = __builtin_amdgcn_mfma_f32_16x16x32_f16(A[rt], B, acc[rt][ct], 0, 0, 0);
        }
    }
    __syncthreads();                              // before clobbering xs region with hs
    // C layout: col = lane&15, row = (lane>>4)*4 + r  -> LDS transpose, coalesced store
    #pragma unroll
    for (int rt = 0; rt < 4; ++rt)
        #pragma unroll
        for (int ct = 0; ct < 4; ++ct)
            #pragma unroll
            for (int r = 0; r < 4; ++r)
                sbuf[(rt * 16 + lg * 4 + r) * HS1_LD + cw + ct * 16 + lr] = (half_t)acc[rt][ct][r];
    __syncthreads();
    for (int idx = tid; idx < 64 * 32; idx += 256) {
        int row = idx >> 5, c8 = (idx & 31) * 8;
        if (row < rows)
            *(float4*)(h1h + (size_t)(base + row) * C1 + c8) = *(const float4*)(sbuf + row * HS1_LD + c8);
    }
    // fused logit1: wave w handles rows w*16..w*16+15; lane covers ch lane*4..+3
    {
        const int c4l = lane * 4;
        const float4 av = *(const float4*)(a_s1 + c4l);
        const float4 dv = *(const float4*)(a_d1 + c4l);
        #pragma unroll
        for (int i = 0; i < 16; ++i) {
            int row = w * 16 + i;
            if (row < rows) {
                float2 rr = *(const float2*)(sbuf + row * HS1_LD + c4l);
                half2_t ha = __builtin_bit_cast(half2_t, rr.x);
                half2_t hb = __builtin_bit_cast(half2_t, rr.y);
                float ps = (float)ha[0] * av.x + (float)ha[1] * av.y + (float)hb[0] * av.z + (float)hb[1] * av.w;
                float pd = (float)ha[0] * dv.x + (float)ha[1] * dv.y + (float)hb[0] * dv.z + (float)hb[1] * dv.w;
                #pragma unroll
                for (int d = 1; d < 16; d <<= 1) {
                    ps += __shfl_xor(ps, d, 64);
                    pd += __shfl_xor(pd, d, 64);
                }
                if ((lane & 15) == 0) {
                    int hh = lane >> 4;
                    l1s[(base + row) * HEADS + hh] = ps;
                    l1d[(base + row) * HEADS + hh] = pd;
                }
            }
        }
    }
}

// ---------------- agg1: grid-stride, half-wave per edge, 8 fp16 ch/lane, 4-deep unroll ----------------
#define NB_AGG 2048
__global__ __launch_bounds__(256) void k_agg1(
    const half_t* __restrict__ h1h, const float* __restrict__ l1s, const float* __restrict__ l1d,
    const int* __restrict__ rowptr, const int* __restrict__ csr_src,
    const float* __restrict__ b1, half_t* __restrict__ out1h) {
    const int tid = threadIdx.x;
    const int lane = tid & 63;
    const int wv = tid >> 6;
    const int half = lane >> 5;                   // edge stream 0/1
    const int l32 = lane & 31;
    const int c8 = l32 * 8;                       // this lane's 8 channels
    const int hh = l32 >> 3;                      // head of those channels
    const float* l1sh = l1s + hh;
    const float4* hrows = (const float4*)h1h;     // 32 float4 per row
    for (int nb = blockIdx.x; nb * 4 < N_NODES; nb += NB_AGG) {
        const int n = nb * 4 + wv;
        if (n >= N_NODES) continue;               // no barriers in kernel
        const int beg = rowptr[n], end = rowptr[n + 1];
        const float4 ldv = *(const float4*)(l1d + (size_t)n * 4);
        const float ldh = (hh & 2) ? ((hh & 1) ? ldv.w : ldv.z) : ((hh & 1) ? ldv.y : ldv.x);
        float a[8] = {0.f, 0.f, 0.f, 0.f, 0.f, 0.f, 0.f, 0.f};
        float dn = 0.f;
        int e = beg + half;
        for (; e + 6 < end; e += 8) {             // 4 edges per half-wave in flight
            int s0 = csr_src[e], s1 = csr_src[e + 2], s2 = csr_src[e + 4], s3 = csr_src[e + 6];
            float4 r0 = hrows[s0 * 32 + l32];
            float4 r1 = hrows[s1 * 32 + l32];
            float4 r2 = hrows[s2 * 32 + l32];
            float4 r3 = hrows[s3 * 32 + l32];
            float g0 = l1sh[s0 * 4] + ldh;
            float g1 = l1sh[s1 * 4] + ldh;
            float g2 = l1sh[s2 * 4] + ldh;
            float g3 = l1sh[s3 * 4] + ldh;
            float w0 = __expf(lrelu(g0));
            float w1 = __expf(lrelu(g1));
            float w2 = __expf(lrelu(g2));
            float w3 = __expf(lrelu(g3));
            dn += (w0 + w1) + (w2 + w3);
            acc8(a, w0, r0);
            acc8(a, w1, r1);
            acc8(a, w2, r2);
            acc8(a, w3, r3);
        }
        for (; e < end; e += 2) {
            int s0 = csr_src[e];
            float4 r0 = hrows[s0 * 32 + l32];
            float g0 = l1sh[s0 * 4] + ldh;
            float w0 = __expf(lrelu(g0));
            dn += w0;
            acc8(a, w0, r0);
        }
        // combine the two half-wave edge streams
        #pragma unroll
        for (int j = 0; j < 8; ++j) a[j] += __shfl_xor(a[j], 32, 64);
        dn += __shfl_xor(dn, 32, 64);
        if (half == 0) {
            const float inv = 1.f / (dn + EPSV);
            const float4 bv0 = *(const float4*)(b1 + c8);
            const float4 bv1 = *(const float4*)(b1 + c8 + 4);
            half2_t p01, p23, p45, p67;
            p01[0] = (half_t)fmaxf(fmaf(a[0], inv, bv0.x), 0.f);
            p01[1] = (half_t)fmaxf(fmaf(a[1], inv, bv0.y), 0.f);
            p23[0] = (half_t)fmaxf(fmaf(a[2], inv, bv0.z), 0.f);
            p23[1] = (half_t)fmaxf(fmaf(a[3], inv, bv0.w), 0.f);
            p45[0] = (half_t)fmaxf(fmaf(a[4], inv, bv1.x), 0.f);
            p45[1] = (half_t)fmaxf(fmaf(a[5], inv, bv1.y), 0.f);
            p67[0] = (half_t)fmaxf(fmaf(a[6], inv, bv1.z), 0.f);
            p67[1] = (half_t)fmaxf(fmaf(a[7], inv, bv1.w), 0.f);
            float4 st;
            st.x = __builtin_bit_cast(float, p01);
            st.y = __builtin_bit_cast(float, p23);
            st.z = __builtin_bit_cast(float, p45);
            st.w = __builtin_bit_cast(float, p67);
            *(float4*)(out1h + (size_t)n * C1 + c8) = st;
        }
    }
}

// ---------------- GEMM2 (MFMA fp16): h2 = out1 @ W2, 32x64 tile, K=256; fused logit2 ----------------
#define XS2_LD 264
#define HS2_LD 72
__global__ __launch_bounds__(256) void k_gemm2(
    const half_t* __restrict__ out1h, const half_t* __restrict__ W2T,
    const float* __restrict__ a_s2, const float* __restrict__ a_d2,
    half_t* __restrict__ h2h, float* __restrict__ l2s, float* __restrict__ l2d) {
    __shared__ half_t xs[32 * XS2_LD];            // 16.9 KB
    __shared__ half_t hs[32 * HS2_LD];            // 4.6 KB
    const int base = blockIdx.x * 32;
    const int rows = min(32, N_NODES - base);
    const int tid = threadIdx.x;
    for (int idx = tid; idx < 32 * 32; idx += 256) {
        int row = idx >> 5, c8 = (idx & 31) * 8;
        half8_t hv = {0, 0, 0, 0, 0, 0, 0, 0};
        if (row < rows) hv = *(const half8_t*)(out1h + (size_t)(base + row) * C1 + c8);
        *(half8_t*)(xs + row * XS2_LD + c8) = hv;
    }
    __syncthreads();
    const int lane = tid & 63;
    const int w = tid >> 6;                       // wave w -> cols 16w..16w+15
    const int lr = lane & 15;
    const int lg = lane >> 4;
    f32x4 acc0, acc1;
    #pragma unroll
    for (int r = 0; r < 4; ++r) { acc0[r] = 0.f; acc1[r] = 0.f; }
    #pragma unroll
    for (int kt = 0; kt < 8; ++kt) {
        const int k0 = kt * 32 + lg * 8;
        half8_t A0 = *(const half8_t*)(xs + lr * XS2_LD + k0);
        half8_t A1 = *(const half8_t*)(xs + (16 + lr) * XS2_LD + k0);
        half8_t B  = *(const half8_t*)(W2T + (size_t)(w * 16 + lr) * C1 + k0);
        acc0 = __builtin_amdgcn_mfma_f32_16x16x32_f16(A0, B, acc0, 0, 0, 0);
        acc1 = __builtin_amdgcn_mfma_f32_16x16x32_f16(A1, B, acc1, 0, 0, 0);
    }
    #pragma unroll
    for (int r = 0; r < 4; ++r) {
        hs[(lg * 4 + r) * HS2_LD + w * 16 + lr] = (half_t)acc0[r];
        hs[(16 + lg * 4 + r) * HS2_LD + w * 16 + lr] = (half_t)acc1[r];
    }
    __syncthreads();
    {
        int idx = tid;                            // 32 rows x 8 chunks == 256
        int row = idx >> 3, c8 = (idx & 7) * 8;
        if (row < rows)
            *(float4*)(h2h + (size_t)(base + row) * HID + c8) = *(const float4*)(hs + row * HS2_LD + c8);
    }
    // fused logit2: wave w handles rows w*8..w*8+7; lane covers one channel
    {
        const float vas = a_s2[lane];
        const float vad = a_d2[lane];
        #pragma unroll
        for (int i = 0; i < 8; ++i) {
            int row = w * 8 + i;
            if (row < rows) {
                float v = (float)hs[row * HS2_LD + lane];
                float ps = v * vas, pd = v * vad;
                #pragma unroll
                for (int d = 1; d < 64; d <<= 1) {
                    ps += __shfl_xor(ps, d, 64);
                    pd += __shfl_xor(pd, d, 64);
                }
                if (lane == 0) { l2s[base + row] = ps; l2d[base + row] = pd; }
            }
        }
    }
}

// ---------------- agg2 + final linear: grid-stride, quarter-wave per edge, barrier hoisted ----------------
__global__ __launch_bounds__(256) void k_agg2(
    const half_t* __restrict__ h2h, const float* __restrict__ l2s, const float* __restrict__ l2d,
    const int* __restrict__ rowptr, const int* __restrict__ csr_src,
    const float* __restrict__ b2, const float* __restrict__ Wl, const float* __restrict__ bl,
    float* __restrict__ out) {
    __shared__ float Wls[HID * OUT_CH];           // 16 KB
    __shared__ float vsh[4][HID];
    const int tid = threadIdx.x;
    const int lane = tid & 63;
    const int wv = tid >> 6;
    for (int i = tid; i < HID * OUT_CH; i += 256) Wls[i] = Wl[i];
    __syncthreads();                              // only barrier: Wls visible to all waves
    const int q = lane >> 4;                      // edge stream 0..3
    const int l16 = lane & 15;                    // float2 index within row
    const float2* h2rows = (const float2*)h2h;    // 16 float2 per row
    const float blv = bl[lane];
    for (int nb = blockIdx.x; nb * 4 < N_NODES; nb += NB_AGG) {
        const int n = nb * 4 + wv;
        if (n >= N_NODES) continue;               // no barriers below (vsh is wave-private)
        const int beg = rowptr[n], end = rowptr[n + 1];
        const float ld = l2d[n];
        float a0 = 0.f, a1 = 0.f, a2 = 0.f, a3 = 0.f, dn = 0.f;
        int e = beg + q;
        for (; e + 12 < end; e += 16) {           // 4 edges per quarter-wave in flight
            int s0 = csr_src[e], s1 = csr_src[e + 4], s2 = csr_src[e + 8], s3 = csr_src[e + 12];
            float2 v0 = h2rows[s0 * 16 + l16];
            float2 v1 = h2rows[s1 * 16 + l16];
            float2 v2 = h2rows[s2 * 16 + l16];
            float2 v3 = h2rows[s3 * 16 + l16];
            float g0 = l2s[s0] + ld;
            float g1 = l2s[s1] + ld;
            float g2 = l2s[s2] + ld;
            float g3 = l2s[s3] + ld;
            float w0 = __expf(lrelu(g0));
            float w1 = __expf(lrelu(g1));
            float w2 = __expf(lrelu(g2));
            float w3 = __expf(lrelu(g3));
            dn += (w0 + w1) + (w2 + w3);
            half2_t p;
            p = __builtin_bit_cast(half2_t, v0.x); a0 = fmaf(w0, (float)p[0], a0); a1 = fmaf(w0, (float)p[1], a1);
            p = __builtin_bit_cast(half2_t, v0.y); a2 = fmaf(w0, (float)p[0], a2); a3 = fmaf(w0, (float)p[1], a3);
            p = __builtin_bit_cast(half2_t, v1.x); a0 = fmaf(w1, (float)p[0], a0); a1 = fmaf(w1, (float)p[1], a1);
            p = __builtin_bit_cast(half2_t, v1.y); a2 = fmaf(w1, (float)p[0], a2); a3 = fmaf(w1, (float)p[1], a3);
            p = __builtin_bit_cast(half2_t, v2.x); a0 = fmaf(w2, (float)p[0], a0); a1 = fmaf(w2, (float)p[1], a1);
            p = __builtin_bit_cast(half2_t, v2.y); a2 = fmaf(w2, (float)p[0], a2); a3 = fmaf(w2, (float)p[1], a3);
            p = __builtin_bit_cast(half2_t, v3.x); a0 = fmaf(w3, (float)p[0], a0); a1 = fmaf(w3, (float)p[1], a1);
            p = __builtin_bit_cast(half2_t, v3.y); a2 = fmaf(w3, (float)p[0], a2); a3 = fmaf(w3, (float)p[1], a3);
        }
        for (; e < end; e += 4) {
            int s = csr_src[e];
            float2 v = h2rows[s * 16 + l16];
            float lg = l2s[s] + ld;
            float w = __expf(lrelu(lg));
            dn += w;
            half2_t p;
            p = __builtin_bit_cast(half2_t, v.x); a0 = fmaf(w, (float)p[0], a0); a1 = fmaf(w, (float)p[1], a1);
            p = __builtin_bit_cast(half2_t, v.y); a2 = fmaf(w, (float)p[0], a2); a3 = fmaf(w, (float)p[1], a3);
        }
        // combine the four quarter-wave edge streams
        a0 += __shfl_xor(a0, 16, 64); a0 += __shfl_xor(a0, 32, 64);
        a1 += __shfl_xor(a1, 16, 64); a1 += __shfl_xor(a1, 32, 64);
        a2 += __shfl_xor(a2, 16, 64); a2 += __shfl_xor(a2, 32, 64);
        a3 += __shfl_xor(a3, 16, 64); a3 += __shfl_xor(a3, 32, 64);
        dn += __shfl_xor(dn, 16, 64); dn += __shfl_xor(dn, 32, 64);
        if (q == 0) {                             // lanes 0-15 write all 64 entries of vsh[wv]
            const float inv = 1.f / (dn + EPSV);
            const float4 bv = *(const float4*)(b2 + l16 * 4);
            float4 vv;
            vv.x = fmaf(a0, inv, bv.x);
            vv.y = fmaf(a1, inv, bv.y);
            vv.z = fmaf(a2, inv, bv.z);
            vv.w = fmaf(a3, inv, bv.w);
            *(float4*)(&vsh[wv][l16 * 4]) = vv;
        }
        // same-wave LDS write->read: compiler inserts lgkmcnt wait; no barrier needed
        float o = blv;
        #pragma unroll
        for (int c2 = 0; c2 < HID; ++c2)
            o = fmaf(vsh[wv][c2], Wls[c2 * OUT_CH + lane], o);
        out[(size_t)n * OUT_CH + lane] = o;
    }
}

extern "C" void kernel_launch(void* const* d_in, const int* in_sizes, int n_in,
                              void* d_out, int out_size, void* d_ws, size_t ws_size,
                              hipStream_t stream) {
    const float* x   = (const float*)d_in[0];
    const int*   ei  = (const int*)d_in[1];
    const float* W1  = (const float*)d_in[2];
    const float* as1 = (const float*)d_in[3];
    const float* ad1 = (const float*)d_in[4];
    const float* b1  = (const float*)d_in[5];
    const float* W2  = (const float*)d_in[6];
    const float* as2 = (const float*)d_in[7];
    const float* ad2 = (const float*)d_in[8];
    const float* b2  = (const float*)d_in[9];
    const float* Wl  = (const float*)d_in[10];
    const float* bl  = (const float*)d_in[11];
    float* out = (float*)d_out;

    char* p = (char*)d_ws;
    auto alloc = [&](size_t bytes) {
        char* r = p;
        p += (bytes + 255) & ~(size_t)255;
        return r;
    };
    int* deg      = (int*)alloc((size_t)N_NODES * 4);
    int* rowptr   = (int*)alloc((size_t)(N_NODES + 1) * 4);
    int* erank    = (int*)alloc((size_t)E_TOT * 4);
    int* csr_src  = (int*)alloc((size_t)E_TOT * 4);
    int* bsum     = (int*)alloc(64 * 4);
    half_t* W1T   = (half_t*)alloc((size_t)IN_CH * C1 * 2);
    half_t* W2T   = (half_t*)alloc((size_t)C1 * HID * 2);
    half_t* xh    = (half_t*)alloc((size_t)N_NODES * IN_CH * 2);
    half_t* h1h   = (half_t*)alloc((size_t)N_NODES * C1 * 2);
    float* l1s    = (float*)alloc((size_t)N_NODES * HEADS * 4);
    float* l1d    = (float*)alloc((size_t)N_NODES * HEADS * 4);
    half_t* out1h = (half_t*)alloc((size_t)N_NODES * C1 * 2);
    half_t* h2h   = (half_t*)alloc((size_t)N_NODES * HID * 2);
    float* l2s    = (float*)alloc((size_t)N_NODES * 4);
    float* l2d    = (float*)alloc((size_t)N_NODES * 4);

    (void)hipMemsetAsync(deg, 0, (size_t)N_NODES * 4, stream);
    k_count_prep<<<NPREP + NXC + NCNT, 256, 0, stream>>>(ei, deg, erank, W1, W2, x, W1T, W2T, xh);
    k_bsum<<<NB_SCAN, 256, 0, stream>>>(deg, bsum);
    k_scanf<<<NB_SCAN, 1024, 0, stream>>>(deg, bsum, rowptr);
    k_scatter<<<(E_TOT + 255) / 256, 256, 0, stream>>>(ei, erank, rowptr, csr_src);
    k_gemm1<<<(N_NODES + 63) / 64, 256, 0, stream>>>(xh, W1T, as1, ad1, h1h, l1s, l1d);
    k_agg1<<<NB_AGG, 256, 0, stream>>>(h1h, l1s, l1d, rowptr, csr_src, b1, out1h);
    k_gemm2<<<(N_NODES + 31) / 32, 256, 0, stream>>>(out1h, W2T, as2, ad2, h2h, l2s, l2d);
    k_agg2<<<NB_AGG, 256, 0, stream>>>(h2h, l2s, l2d, rowptr, csr_src, b2, Wl, bl, out);
}